// Round 5
// baseline (371.171 us; speedup 1.0000x reference)
//
#include <hip/hip_runtime.h>
#include <hip/hip_bf16.h>

// 3x3 conv pad=1 stride=1, NHWC fp32 -> bf16 MFMA implicit GEMM.
//   M = 32*56*56 = 100352, N = 256, K = 9*128 = 1152
// R5: NO LDS, NO BARRIERS. R2-R4 all plateaued at ~100us / MfmaUtil 24%
// regardless of conflicts or double-buffering -> the __syncthreads-vmcnt(0)
// drain structure was the limiter. Fragments are loaded directly from global
// (packed layouts make each lane's 16B fragment chunk addressable), K-loop
// fully unrolled with explicit 1-iter register prefetch -> compiler emits
// fine-grained vmcnt(N) interleave (AITER-style), loads never drained.

#define NIMG 32
#define HH 56
#define WW 56
#define PH 58
#define PW 58
#define CIN 128
#define COUT 256
#define KTOT 1152
#define PAD_ELEMS (NIMG * PH * PW * CIN)
#define KITERS 36            // K / 32

typedef __attribute__((ext_vector_type(8))) short bf16x8;
typedef __attribute__((ext_vector_type(4))) short s16x4;
typedef __attribute__((ext_vector_type(4))) float f32x4;

__device__ __forceinline__ short f2bf(float x) {
    union { __hip_bfloat16 b; short s; } u;
    u.b = __float2bfloat16(x);
    return u.s;
}

// ---- pack 1: fp32 NHWC -> padded bf16 (32,58,58,128), zero halo -------------
__global__ __launch_bounds__(256) void pack_input(const float* __restrict__ in,
                                                  short* __restrict__ pad) {
    const int tid  = blockIdx.x * 256 + threadIdx.x;
    const int flat = tid * 8;
    const int c8   = flat & (CIN - 1);
    const int rest = flat >> 7;
    const int iw   = rest % PW;
    const int r2   = rest / PW;
    const int ih   = r2 % PH;
    const int img  = r2 / PH;
    bf16x8 v = (bf16x8)0;
    if (ih >= 1 && ih <= HH && iw >= 1 && iw <= WW) {
        const float* p = in + (((size_t)(img * HH + ih - 1) * WW + (iw - 1)) * CIN + c8);
        const float4 x0 = *(const float4*)p;
        const float4 x1 = *(const float4*)(p + 4);
        v.s0 = f2bf(x0.x); v.s1 = f2bf(x0.y); v.s2 = f2bf(x0.z); v.s3 = f2bf(x0.w);
        v.s4 = f2bf(x1.x); v.s5 = f2bf(x1.y); v.s6 = f2bf(x1.z); v.s7 = f2bf(x1.w);
    }
    *(bf16x8*)(pad + flat) = v;
}

// ---- pack 2: weights (K=1152, N=256) fp32 -> bf16 transposed [n][k] ---------
__global__ __launch_bounds__(256) void pack_wgt(const float* __restrict__ w,
                                                short* __restrict__ wt) {
    __shared__ short tile[32][33];
    const int k0 = blockIdx.x * 32;
    const int n0 = blockIdx.y * 32;
    const int t  = threadIdx.x;
    {
        const int kl  = t >> 3;
        const int nl4 = (t & 7) * 4;
        const float4 x = *(const float4*)(w + (size_t)(k0 + kl) * COUT + n0 + nl4);
        tile[kl][nl4 + 0] = f2bf(x.x);
        tile[kl][nl4 + 1] = f2bf(x.y);
        tile[kl][nl4 + 2] = f2bf(x.z);
        tile[kl][nl4 + 3] = f2bf(x.w);
    }
    __syncthreads();
    {
        const int nl  = t >> 3;
        const int kl4 = (t & 7) * 4;
        s16x4 v;
        v.x = tile[kl4 + 0][nl];
        v.y = tile[kl4 + 1][nl];
        v.z = tile[kl4 + 2][nl];
        v.w = tile[kl4 + 3][nl];
        *(s16x4*)(wt + (size_t)(n0 + nl) * KTOT + k0 + kl4) = v;
    }
}

// ---- GEMM: 128x128 block, 4 waves x (64x64), direct-from-global fragments --
// Lane (fq=l>>4, fr=l&15): A-frag i = apad row (m-tile + i*16 + fr), k-chunk
// fq -> 16B load, rows 256B apart. B-frag j = bwt row (n-tile + j*16 + fr),
// stride 2304B. All per-iter offsets compile-time (full unroll); B offsets and
// plane-0 A offsets fold into the 13-bit global_load immediate.
__global__ __launch_bounds__(256, 2) void conv_mfma(const short* __restrict__ apad,
                                                    const short* __restrict__ bwt,
                                                    const float* __restrict__ bias,
                                                    float* __restrict__ out) {
    const int t  = threadIdx.x;
    const int l  = t & 63;
    const int w  = t >> 6;
    const int m0 = blockIdx.y * 128;
    const int n0 = blockIdx.x * 128;

    const int wm = w & 1;
    const int wn = w >> 1;
    const int fr = l & 15;
    const int fq = l >> 4;

    // per-lane fragment base pointers
    const short* abase[4];
#pragma unroll
    for (int i = 0; i < 4; ++i) {
        const int m   = m0 + wm * 64 + i * 16 + fr;
        const int img = m / (HH * WW);
        const int rem = m - img * (HH * WW);
        const int oh  = rem / WW;
        const int ow  = rem - oh * WW;
        abase[i] = apad + ((img * PH + oh) * PW + ow) * CIN + fq * 8;
    }
    const short* bbase[4];
#pragma unroll
    for (int j = 0; j < 4; ++j)
        bbase[j] = bwt + (n0 + wn * 64 + j * 16 + fr) * KTOT + fq * 8;

    f32x4 acc[4][4];
#pragma unroll
    for (int i = 0; i < 4; ++i)
#pragma unroll
        for (int j = 0; j < 4; ++j) { f32x4 z = {0.f, 0.f, 0.f, 0.f}; acc[i][j] = z; }

#define AOFF(KT) ((((KT) >> 2) / 3 * PW + (((KT) >> 2) % 3)) * CIN + ((KT) & 3) * 32)
#define BOFF(KT) ((KT) * 32)

    bf16x8 ac[4], bc[4];
#pragma unroll
    for (int i = 0; i < 4; ++i) ac[i] = *(const bf16x8*)(abase[i] + AOFF(0));
#pragma unroll
    for (int j = 0; j < 4; ++j) bc[j] = *(const bf16x8*)(bbase[j] + BOFF(0));

#pragma unroll
    for (int kt = 0; kt < KITERS; ++kt) {
        bf16x8 an[4], bn[4];
        if (kt + 1 < KITERS) {
            const int ao = AOFF(kt + 1), bo = BOFF(kt + 1);
#pragma unroll
            for (int i = 0; i < 4; ++i) an[i] = *(const bf16x8*)(abase[i] + ao);
#pragma unroll
            for (int j = 0; j < 4; ++j) bn[j] = *(const bf16x8*)(bbase[j] + bo);
        }
#pragma unroll
        for (int i = 0; i < 4; ++i)
#pragma unroll
            for (int j = 0; j < 4; ++j)
                acc[i][j] = __builtin_amdgcn_mfma_f32_16x16x32_bf16(ac[i], bc[j], acc[i][j], 0, 0, 0);
        if (kt + 1 < KITERS) {
#pragma unroll
            for (int i = 0; i < 4; ++i) { ac[i] = an[i]; bc[i] = bn[i]; }
        }
    }
#undef AOFF
#undef BOFF

    // ---- epilogue: bias + ReLU. D: col(N)=lane&15, row(M)=quad*4+reg (m89)
#pragma unroll
    for (int j = 0; j < 4; ++j) {
        const int n  = n0 + wn * 64 + j * 16 + fr;
        const float bj = bias[n];
#pragma unroll
        for (int i = 0; i < 4; ++i) {
            const int mrow = m0 + wm * 64 + i * 16 + fq * 4;
#pragma unroll
            for (int r = 0; r < 4; ++r) {
                const float v = acc[i][j][r] + bj;
                out[(size_t)(mrow + r) * COUT + n] = v > 0.f ? v : 0.f;
            }
        }
    }
}

extern "C" void kernel_launch(void* const* d_in, const int* in_sizes, int n_in,
                              void* d_out, int out_size, void* d_ws, size_t ws_size,
                              hipStream_t stream) {
    const float* in   = (const float*)d_in[0];
    const float* wgt  = (const float*)d_in[1];
    const float* bias = (const float*)d_in[2];
    float* out = (float*)d_out;

    short* pad = (short*)d_ws;
    short* wt  = (short*)d_ws + PAD_ELEMS;

    pack_input<<<PAD_ELEMS / 8 / 256, 256, 0, stream>>>(in, pad);
    pack_wgt<<<dim3(KTOT / 32, COUT / 32), 256, 0, stream>>>(wgt, wt);

    dim3 grid(COUT / 128, (NIMG * HH * WW) / 128);   // (2, 784)
    conv_mfma<<<grid, 256, 0, stream>>>(pad, wt, bias, out);
}

// Round 6
// 232.634 us; speedup vs baseline: 1.5955x; 1.5955x over previous
//
#include <hip/hip_runtime.h>
#include <hip/hip_bf16.h>

// 3x3 conv pad=1 stride=1, NHWC fp32 -> bf16 MFMA implicit GEMM.
//   M = 32*56*56 = 100352, N = 256, K = 9*128 = 1152
// R6: AITER-style K-loop. __syncthreads' mandatory vmcnt(0) was the plateau
// (R2-R4 all ~100us regardless of conflicts/dbuf; R5 no-LDS regressed).
// Raw s_barrier (inline asm, no auto-drain) + explicit s_waitcnt vmcnt(4):
// 4-buffer LDS ring, stage k+3 issued at iter k, drained 2+ iters later.
// Tail peeled with vmcnt 4/4/0. XCD swizzle pairs A-sharing blocks.

#define NIMG 32
#define HH 56
#define WW 56
#define PH 58
#define PW 58
#define CIN 128
#define COUT 256
#define KTOT 1152
#define PAD_ELEMS (NIMG * PH * PW * CIN)
#define BK 32
#define KITERS 36

typedef __attribute__((ext_vector_type(8))) short bf16x8;
typedef __attribute__((ext_vector_type(4))) short s16x4;
typedef __attribute__((ext_vector_type(4))) float f32x4;

__device__ __forceinline__ short f2bf(float x) {
    union { __hip_bfloat16 b; short s; } u;
    u.b = __float2bfloat16(x);
    return u.s;
}

typedef const void __attribute__((address_space(1)))* gas1_t;
typedef void __attribute__((address_space(3)))* las3_t;
__device__ __forceinline__ void async16(short* lds, const short* g) {
    __builtin_amdgcn_global_load_lds((gas1_t)g, (las3_t)lds, 16, 0, 0);
}

// ---- pack 1: fp32 NHWC -> padded bf16 (32,58,58,128), zero halo -------------
__global__ __launch_bounds__(256) void pack_input(const float* __restrict__ in,
                                                  short* __restrict__ pad) {
    const int tid  = blockIdx.x * 256 + threadIdx.x;
    const int flat = tid * 8;
    const int c8   = flat & (CIN - 1);
    const int rest = flat >> 7;
    const int iw   = rest % PW;
    const int r2   = rest / PW;
    const int ih   = r2 % PH;
    const int img  = r2 / PH;
    bf16x8 v = (bf16x8)0;
    if (ih >= 1 && ih <= HH && iw >= 1 && iw <= WW) {
        const float* p = in + (((size_t)(img * HH + ih - 1) * WW + (iw - 1)) * CIN + c8);
        const float4 x0 = *(const float4*)p;
        const float4 x1 = *(const float4*)(p + 4);
        v.s0 = f2bf(x0.x); v.s1 = f2bf(x0.y); v.s2 = f2bf(x0.z); v.s3 = f2bf(x0.w);
        v.s4 = f2bf(x1.x); v.s5 = f2bf(x1.y); v.s6 = f2bf(x1.z); v.s7 = f2bf(x1.w);
    }
    *(bf16x8*)(pad + flat) = v;
}

// ---- pack 2: weights (K=1152, N=256) fp32 -> bf16 transposed [n][k] ---------
__global__ __launch_bounds__(256) void pack_wgt(const float* __restrict__ w,
                                                short* __restrict__ wt) {
    __shared__ short tile[32][33];
    const int k0 = blockIdx.x * 32;
    const int n0 = blockIdx.y * 32;
    const int t  = threadIdx.x;
    {
        const int kl  = t >> 3;
        const int nl4 = (t & 7) * 4;
        const float4 x = *(const float4*)(w + (size_t)(k0 + kl) * COUT + n0 + nl4);
        tile[kl][nl4 + 0] = f2bf(x.x);
        tile[kl][nl4 + 1] = f2bf(x.y);
        tile[kl][nl4 + 2] = f2bf(x.z);
        tile[kl][nl4 + 3] = f2bf(x.w);
    }
    __syncthreads();
    {
        const int nl  = t >> 3;
        const int kl4 = (t & 7) * 4;
        s16x4 v;
        v.x = tile[kl4 + 0][nl];
        v.y = tile[kl4 + 1][nl];
        v.z = tile[kl4 + 2][nl];
        v.w = tile[kl4 + 3][nl];
        *(s16x4*)(wt + (size_t)(n0 + nl) * KTOT + k0 + kl4) = v;
    }
}

// ---- GEMM: 128x128 tile, BK=32, 4-deep LDS ring, manual vmcnt pipeline -----
// Swizzle (verified conflict-free in R3/R4): superrow (2 rows, 128B = 8 x 16B
// chunks); phys chunk p holds logical chunk p ^ (s&7), logical L = (row&1)*4
// + kchunk. Staging chunk c = j*256 + t -> superrow (t>>3)+32j, phys t&7.
__global__ __launch_bounds__(256, 2) void conv_mfma(const short* __restrict__ apad,
                                                    const short* __restrict__ bwt,
                                                    const float* __restrict__ bias,
                                                    float* __restrict__ out) {
    __shared__ short As[4][128 * BK];   // 32 KB
    __shared__ short Bs[4][128 * BK];   // 32 KB (total 64 KB -> 2 blocks/CU)

    const int t = threadIdx.x;
    const int l = t & 63;
    const int w = t >> 6;

    // XCD-friendly decode: L = 16a+8b+c -> n-blk b, m-blk 8a+c. The two
    // blocks sharing an A-tile differ by 8 in L -> same XCD (%8), near in time.
    const int L  = blockIdx.x;
    const int m0 = (((L >> 4) << 3) | (L & 7)) * 128;
    const int n0 = ((L >> 3) & 1) * 128;

    // staging sources (R4 map): logical chunk Lc = (t&7)^((t>>3)&7)
    const int Lc = (t & 7) ^ ((t >> 3) & 7);
    const int kc = Lc & 3;
    int abase[2], bbase[2];
#pragma unroll
    for (int j = 0; j < 2; ++j) {
        const int r   = 2 * (t >> 3) + (Lc >> 2) + j * 64;
        const int m   = m0 + r;
        const int img = m / (HH * WW);
        const int rem = m - img * (HH * WW);
        const int oh  = rem / WW;
        const int ow  = rem - oh * WW;
        abase[j] = ((img * PH + oh) * PW + ow) * CIN + kc * 8;
        bbase[j] = (n0 + r) * KTOT + kc * 8;
    }

    f32x4 acc[4][4];
#pragma unroll
    for (int i = 0; i < 4; ++i)
#pragma unroll
        for (int j = 0; j < 4; ++j) { f32x4 z = {0.f, 0.f, 0.f, 0.f}; acc[i][j] = z; }

    const int wm = w & 1;
    const int wn = w >> 1;
    const int fr = l & 15;
    const int fq = l >> 4;

#define STAGE(KT) do {                                                        \
        const int _b    = (KT) & 3;                                           \
        const int _fhw  = (KT) >> 2;                                          \
        const int _fh   = _fhw / 3;                                           \
        const int _fw   = _fhw - _fh * 3;                                     \
        const int _aoff = (_fh * PW + _fw) * CIN + ((KT) & 3) * 32;           \
        const int _boff = (KT) * BK;                                          \
        _Pragma("unroll")                                                     \
        for (int _j = 0; _j < 2; ++_j) {                                      \
            async16(&As[_b][(_j * 256 + w * 64) * 8], apad + abase[_j] + _aoff); \
            async16(&Bs[_b][(_j * 256 + w * 64) * 8], bwt + bbase[_j] + _boff);  \
        }                                                                     \
    } while (0)

#define FRAG(BASE, R) \
    (*(const bf16x8*)((BASE) + (((R) >> 1) << 6) + \
     (((((R) & 1) << 2) | fq) ^ (((R) >> 1) & 7)) * 8))

#define READF(KT, AF, BF) do {                                                \
        const short* _as = As[(KT) & 3];                                      \
        const short* _bs = Bs[(KT) & 3];                                      \
        _Pragma("unroll")                                                     \
        for (int _i = 0; _i < 4; ++_i) (AF)[_i] = FRAG(_as, wm * 64 + _i * 16 + fr); \
        _Pragma("unroll")                                                     \
        for (int _j = 0; _j < 4; ++_j) (BF)[_j] = FRAG(_bs, wn * 64 + _j * 16 + fr); \
    } while (0)

#define COMPUTE(AF, BF) do {                                                  \
        _Pragma("unroll")                                                     \
        for (int _i = 0; _i < 4; ++_i)                                        \
            _Pragma("unroll")                                                 \
            for (int _j = 0; _j < 4; ++_j)                                    \
                acc[_i][_j] = __builtin_amdgcn_mfma_f32_16x16x32_bf16(        \
                    (AF)[_i], (BF)[_j], acc[_i][_j], 0, 0, 0);                \
    } while (0)

#define WAIT4_BAR() do {                                                      \
        asm volatile("s_waitcnt vmcnt(4) lgkmcnt(0)" ::: "memory");           \
        asm volatile("s_barrier" ::: "memory");                               \
    } while (0)
#define WAIT0_BAR() do {                                                      \
        asm volatile("s_waitcnt vmcnt(0) lgkmcnt(0)" ::: "memory");           \
        asm volatile("s_barrier" ::: "memory");                               \
    } while (0)

    bf16x8 a0[4], b0[4], a1[4], b1[4];

    // prologue: 3 stages in flight; consume S0
    STAGE(0); STAGE(1); STAGE(2);
    asm volatile("s_waitcnt vmcnt(8)" ::: "memory");
    asm volatile("s_barrier" ::: "memory");
    READF(0, a0, b0);

    // main: pairs kt=0,2,..,30 (tiles 0..31); each half: wait S(k+1), barrier,
    // stage S(k+3), read frags(k+1), compute tile k.
    for (int kt = 0; kt < 32; kt += 2) {
        WAIT4_BAR();
        STAGE(kt + 3);
        READF(kt + 1, a1, b1);
        COMPUTE(a0, b0);
        WAIT4_BAR();
        STAGE(kt + 4);
        READF(kt + 2, a0, b0);
        COMPUTE(a1, b1);
    }
    // peel 32..35
    WAIT4_BAR();            // S33 landed; S34,S35... S35 staged below
    STAGE(35);
    READF(33, a1, b1);
    COMPUTE(a0, b0);        // tile 32
    WAIT4_BAR();            // S34 landed (S35 in flight)
    READF(34, a0, b0);
    COMPUTE(a1, b1);        // tile 33
    WAIT0_BAR();            // S35 landed
    READF(35, a1, b1);
    COMPUTE(a0, b0);        // tile 34
    COMPUTE(a1, b1);        // tile 35 (compiler inserts lgkmcnt)

    // ---- epilogue: bias + ReLU. D: col(N)=lane&15, row(M)=quad*4+reg (m89)
#pragma unroll
    for (int j = 0; j < 4; ++j) {
        const int n  = n0 + wn * 64 + j * 16 + fr;
        const float bj = bias[n];
#pragma unroll
        for (int i = 0; i < 4; ++i) {
            const int mrow = m0 + wm * 64 + i * 16 + fq * 4;
#pragma unroll
            for (int r = 0; r < 4; ++r) {
                const float v = acc[i][j][r] + bj;
                out[(size_t)(mrow + r) * COUT + n] = v > 0.f ? v : 0.f;
            }
        }
    }
#undef STAGE
#undef FRAG
#undef READF
#undef COMPUTE
#undef WAIT4_BAR
#undef WAIT0_BAR
}

extern "C" void kernel_launch(void* const* d_in, const int* in_sizes, int n_in,
                              void* d_out, int out_size, void* d_ws, size_t ws_size,
                              hipStream_t stream) {
    const float* in   = (const float*)d_in[0];
    const float* wgt  = (const float*)d_in[1];
    const float* bias = (const float*)d_in[2];
    float* out = (float*)d_out;

    short* pad = (short*)d_ws;
    short* wt  = (short*)d_ws + PAD_ELEMS;

    pack_input<<<PAD_ELEMS / 8 / 256, 256, 0, stream>>>(in, pad);
    pack_wgt<<<dim3(KTOT / 32, COUT / 32), 256, 0, stream>>>(wgt, wt);

    conv_mfma<<<1568, 256, 0, stream>>>(pad, wt, bias, out);
}